// Round 3
// baseline (430.902 us; speedup 1.0000x reference)
//
#include <hip/hip_runtime.h>

#define N_SIG (1 << 23)   // 8388608
#define N2    (1 << 24)   // padded FFT length = 256^3
#define MH    (1 << 23)   // half length M = 2^23 = 256*256*128

// ---------------------------------------------------------------------------
// complex helpers
// ---------------------------------------------------------------------------
__device__ __forceinline__ float2 cadd(float2 a, float2 b) { return make_float2(a.x + b.x, a.y + b.y); }
__device__ __forceinline__ float2 csub(float2 a, float2 b) { return make_float2(a.x - b.x, a.y - b.y); }
__device__ __forceinline__ float2 cmul(float2 a, float2 b) {
    return make_float2(fmaf(a.x, b.x, -(a.y * b.y)), fmaf(a.x, b.y, a.y * b.x));
}
__device__ __forceinline__ float2 mulnegi(float2 a) { return make_float2(a.y, -a.x); }  // -i*a

// exp(-2*pi*i*f), f in revolutions (v_sin/v_cos take revolutions)
__device__ __forceinline__ float2 twid(float f) {
    float s, c;
#if __has_builtin(__builtin_amdgcn_sinf) && __has_builtin(__builtin_amdgcn_cosf)
    s = __builtin_amdgcn_sinf(f);
    c = __builtin_amdgcn_cosf(f);
#else
    __sincosf(6.28318530717958647693f * f, &s, &c);
#endif
    return make_float2(c, -s);
}

// radix-4 DIF butterfly = natural-order 4-point DFT (negative exponent)
__device__ __forceinline__ void bfly4(float2 c0, float2 c1, float2 c2, float2 c3,
                                      float2& e0, float2& e1, float2& e2, float2& e3) {
    float2 d0 = cadd(c0, c2), d1 = csub(c0, c2);
    float2 d2 = cadd(c1, c3), d3 = mulnegi(csub(c1, c3));
    e0 = cadd(d0, d2); e1 = cadd(d1, d3); e2 = csub(d0, d2); e3 = csub(d1, d3);
}

// 16-point DFT, natural order in/out
__device__ __forceinline__ void fft16(float2 v[16]) {
    const float C1 = 0.92387953251128675613f;
    const float S1 = 0.38268343236508977173f;
    const float RH = 0.70710678118654752440f;
    const float2 W1 = make_float2( C1, -S1);
    const float2 W2 = make_float2( RH, -RH);
    const float2 W3 = make_float2( S1, -C1);
    const float2 W6 = make_float2(-RH, -RH);
    const float2 W9 = make_float2(-C1,  S1);
    float2 t[16];
    { float2 e0,e1,e2,e3; bfly4(v[0],v[4],v[8],v[12], e0,e1,e2,e3);
      t[0]=e0; t[1]=e1; t[2]=e2; t[3]=e3; }
    { float2 e0,e1,e2,e3; bfly4(v[1],v[5],v[9],v[13], e0,e1,e2,e3);
      t[4]=e0; t[5]=cmul(e1,W1); t[6]=cmul(e2,W2); t[7]=cmul(e3,W3); }
    { float2 e0,e1,e2,e3; bfly4(v[2],v[6],v[10],v[14], e0,e1,e2,e3);
      t[8]=e0; t[9]=cmul(e1,W2); t[10]=mulnegi(e2); t[11]=cmul(e3,W6); }
    { float2 e0,e1,e2,e3; bfly4(v[3],v[7],v[11],v[15], e0,e1,e2,e3);
      t[12]=e0; t[13]=cmul(e1,W3); t[14]=cmul(e2,W6); t[15]=cmul(e3,W9); }
    { float2 e0,e1,e2,e3; bfly4(t[0],t[4],t[8],t[12], e0,e1,e2,e3);
      v[0]=e0; v[4]=e1; v[8]=e2; v[12]=e3; }
    { float2 e0,e1,e2,e3; bfly4(t[1],t[5],t[9],t[13], e0,e1,e2,e3);
      v[1]=e0; v[5]=e1; v[9]=e2; v[13]=e3; }
    { float2 e0,e1,e2,e3; bfly4(t[2],t[6],t[10],t[14], e0,e1,e2,e3);
      v[2]=e0; v[6]=e1; v[10]=e2; v[14]=e3; }
    { float2 e0,e1,e2,e3; bfly4(t[3],t[7],t[11],t[15], e0,e1,e2,e3);
      v[3]=e0; v[7]=e1; v[11]=e2; v[15]=e3; }
}

// 8-point DFT, natural order in/out (DIT: two 4-point + combine)
__device__ __forceinline__ void fft8(float2 v[8]) {
    const float RH = 0.70710678118654752440f;
    float2 e0,e1,e2,e3, o0,o1,o2,o3;
    bfly4(v[0],v[2],v[4],v[6], e0,e1,e2,e3);
    bfly4(v[1],v[3],v[5],v[7], o0,o1,o2,o3);
    o1 = cmul(o1, make_float2( RH,-RH));   // W8^1
    o2 = mulnegi(o2);                      // W8^2
    o3 = cmul(o3, make_float2(-RH,-RH));   // W8^3
    v[0]=cadd(e0,o0); v[4]=csub(e0,o0);
    v[1]=cadd(e1,o1); v[5]=csub(e1,o1);
    v[2]=cadd(e2,o2); v[6]=csub(e2,o2);
    v[3]=cadd(e3,o3); v[7]=csub(e3,o3);
}

// W[k] = FA[k]*FX[k] = -(i/4)*(zk^2 - conj(zr)^2), zk=Z[k], zr=Z[N2-k]
__device__ __forceinline__ float2 Wfun(float2 zk, float2 zr) {
    float ax = zk.x*zk.x - zk.y*zk.y, ay = 2.f*zk.x*zk.y;
    float bx = zr.x*zr.x - zr.y*zr.y, by = -2.f*zr.x*zr.y;
    float dx = ax - bx, dy = ay - by;
    return make_float2(0.25f*dy, -0.25f*dx);
}

// ---------------------------------------------------------------------------
// MODE 0: fwd stage A  (N2, radix-256, l=65536, m=1), pack fused
// MODE 1: fwd stage B  (N2, radix-256, l=256,   m=256)
// MODE 2: fwd stage C  (N2, radix-256, l=1,     m=65536)
// MODE 3: inv stage A  (M,  radix-256, l=32768, m=1), Hermitian-pack fused
// MODE 4: inv stage B  (M,  radix-256, l=128,   m=256)
// MODE 5: inv stage C  (M,  radix-128, l=1,     m=65536), real-interleave out
// ---------------------------------------------------------------------------
template<int MODE>
__global__ __launch_bounds__(256, 5)
void fft_pass(const float* __restrict__ ga, const float* __restrict__ gx,
              const float2* __restrict__ gin, float2* __restrict__ gout,
              float2* __restrict__ gout2) {
    __shared__ float2 tile[4096];   // 32 KB
    const int t   = threadIdx.x;
    const int blk = blockIdx.x;

    if constexpr (MODE == 5) {
        // ---- radix-128 pass: 32 rows x 128 points, slot in [0,8) ----
        const int row  = t & 31;
        const int slot = t >> 5;
        const int mask = row & 15;
        const int bi   = blk * 32 + row;

        float2 va[8], vb[8];
        #pragma unroll
        for (int q2 = 0; q2 < 8; ++q2)
            va[q2] = gin[bi + ((slot + 16 * q2) << 16)];
        #pragma unroll
        for (int q2 = 0; q2 < 8; ++q2)
            vb[q2] = gin[bi + ((slot + 8 + 16 * q2) << 16)];
        fft8(va); fft8(vb);
        #pragma unroll
        for (int r2 = 1; r2 < 8; ++r2)
            va[r2] = cmul(va[r2], twid((float)(slot * r2) * (1.0f / 128.0f)));
        #pragma unroll
        for (int r2 = 1; r2 < 8; ++r2)
            vb[r2] = cmul(vb[r2], twid((float)((slot + 8) * r2) * (1.0f / 128.0f)));
        #pragma unroll
        for (int r2 = 0; r2 < 8; ++r2)
            tile[row * 128 + ((slot + 16 * r2) ^ mask)] = va[r2];
        #pragma unroll
        for (int r2 = 0; r2 < 8; ++r2)
            tile[row * 128 + ((slot + 8 + 16 * r2) ^ mask)] = vb[r2];
        __syncthreads();

        float2 w[16];
        #pragma unroll
        for (int q1 = 0; q1 < 16; ++q1)
            w[q1] = tile[row * 128 + ((q1 + 16 * slot) ^ mask)];
        __syncthreads();
        fft16(w);   // w[r1] -> output r = slot + 8*r1

        // keep r < 64 (=> output index m < 2^22), interleave y[2m],y[2m+1]
        const float sc = 1.0f / 8388608.0f;
        #pragma unroll
        for (int r1 = 0; r1 < 8; ++r1) {
            int r = slot + 8 * r1;
            tile[row * 64 + (r ^ mask)] = make_float2(w[r1].x * sc, -w[r1].y * sc);
        }
        __syncthreads();
        const int k0 = blk * 32;
        #pragma unroll
        for (int i = 0; i < 8; ++i) {
            int s = t + 256 * i;           // 32*64 = 2048 float2
            int r = s >> 5, kl = s & 31;
            gout2[k0 + kl + (r << 16)] = tile[kl * 64 + (r ^ (kl & 15))];
        }
        return;
    } else {
        // ---- radix-256 pass: 16 rows x 256 points, slot in [0,16) ----
        const int row  = t & 15;
        const int slot = t >> 4;
        const int mask = row;
        float2 v[16];
        int jt = 0;

        if constexpr (MODE == 0) {          // fwd A, pack fused (q>=128 zero)
            int j = blk * 16 + row;
            jt = j;
            #pragma unroll
            for (int u2 = 0; u2 < 16; ++u2) {
                if (u2 < 8) {
                    int g = j + ((slot + 16 * u2) << 16);  // < N_SIG
                    v[u2] = make_float2(ga[g], gx[g]);
                } else {
                    v[u2] = make_float2(0.f, 0.f);
                }
            }
        } else if constexpr (MODE == 3) {   // inv A, Hermitian pack fused
            int j = blk * 16 + row;
            jt = j;
            #pragma unroll
            for (int u2 = 0; u2 < 16; ++u2) {
                int tp = j + ((slot + 16 * u2) << 15);     // [0, M)
                float2 z1 = gin[tp];                       // Z[t]
                float2 z2 = gin[tp + MH];                  // Z[t+M]
                float2 z3 = gin[(N2 - tp) & (N2 - 1)];     // Z[N2-t]
                float2 z4 = gin[MH - tp];                  // Z[M-t]
                float2 w1 = Wfun(z1, z3);                  // W[t]
                float2 w2 = Wfun(z2, z4);                  // W[t+M]
                float2 S = make_float2(0.5f * (w1.x + w2.x), 0.5f * (w1.y + w2.y));
                float2 D = make_float2(0.5f * (w1.x - w2.x), 0.5f * (w1.y - w2.y));
                float2 tw = twid((float)tp * (1.0f / 16777216.0f));
                float c = tw.x, s = -tw.y;                 // e^{+2pi i t/N2}
                float2 T = make_float2(c * D.x - s * D.y, c * D.y + s * D.x);
                // U = S + i*T ; P = conj(U)
                v[u2] = make_float2(S.x - T.y, -(S.y + T.x));
            }
        } else if constexpr (MODE == 1) {   // fwd B
            int jB = blk >> 4, k0 = (blk & 15) * 16;
            int bi = k0 + row + (jB << 8);
            jt = jB;
            #pragma unroll
            for (int u2 = 0; u2 < 16; ++u2)
                v[u2] = gin[bi + ((slot + 16 * u2) << 16)];
        } else if constexpr (MODE == 4) {   // inv B (half length: stride 2^15)
            int jB = blk >> 4, k0 = (blk & 15) * 16;
            int bi = k0 + row + (jB << 8);
            jt = jB;
            #pragma unroll
            for (int u2 = 0; u2 < 16; ++u2)
                v[u2] = gin[bi + ((slot + 16 * u2) << 15)];
        } else {                            // MODE 2: fwd C
            int bi = blk * 16 + row;
            #pragma unroll
            for (int u2 = 0; u2 < 16; ++u2)
                v[u2] = gin[bi + ((slot + 16 * u2) << 16)];
        }

        // layer 1: FFT16 over u2, inter-layer twiddle W256^{slot*r}
        fft16(v);
        #pragma unroll
        for (int r = 1; r < 16; ++r)
            v[r] = cmul(v[r], twid((float)(slot * r) * (1.0f / 256.0f)));
        #pragma unroll
        for (int r = 0; r < 16; ++r)
            tile[row * 256 + ((slot + 16 * r) ^ mask)] = v[r];
        __syncthreads();

        // layer 2: FFT16 over u1
        float2 w[16];
        #pragma unroll
        for (int u1 = 0; u1 < 16; ++u1)
            w[u1] = tile[row * 256 + ((u1 + (slot << 4)) ^ mask)];
        __syncthreads();
        fft16(w);

        // outer twiddle W_{R*l}^{jt*r}, r = slot + 16*v2
        if constexpr (MODE == 0) {
            #pragma unroll
            for (int v2 = 0; v2 < 16; ++v2) {
                int r = slot + 16 * v2;
                w[v2] = cmul(w[v2], twid((float)(jt * r) * (1.0f / 16777216.0f)));
            }
        } else if constexpr (MODE == 3) {
            #pragma unroll
            for (int v2 = 0; v2 < 16; ++v2) {
                int r = slot + 16 * v2;
                w[v2] = cmul(w[v2], twid((float)(jt * r) * (1.0f / 8388608.0f)));
            }
        } else if constexpr (MODE == 1) {
            #pragma unroll
            for (int v2 = 0; v2 < 16; ++v2) {
                int r = slot + 16 * v2;
                w[v2] = cmul(w[v2], twid((float)(jt * r) * (1.0f / 65536.0f)));
            }
        } else if constexpr (MODE == 4) {
            #pragma unroll
            for (int v2 = 0; v2 < 16; ++v2) {
                int r = slot + 16 * v2;
                w[v2] = cmul(w[v2], twid((float)(jt * r) * (1.0f / 32768.0f)));
            }
        }

        // stage to LDS, cooperative coalesced store
        #pragma unroll
        for (int v2 = 0; v2 < 16; ++v2)
            tile[row * 256 + ((slot + (v2 << 4)) ^ mask)] = w[v2];
        __syncthreads();

        if constexpr (MODE == 0 || MODE == 3) {       // out[256 j + r]: linear
            int base = blk << 12;
            #pragma unroll
            for (int i = 0; i < 16; ++i) {
                int s = t + 256 * i;
                int rr = s >> 8, c = s & 255;
                gout[base + s] = tile[rr * 256 + (c ^ rr)];
            }
        } else if constexpr (MODE == 1 || MODE == 4) {// out[k + 65536 j + 256 r]
            int jB = blk >> 4, k0 = (blk & 15) * 16;
            int base = k0 + (jB << 16);
            #pragma unroll
            for (int i = 0; i < 16; ++i) {
                int s = t + 256 * i;
                int r = s >> 4, kl = s & 15;
                gout[base + kl + (r << 8)] = tile[kl * 256 + (r ^ kl)];
            }
        } else {                                      // MODE 2: out[k + 65536 r]
            int k0 = blk * 16;
            #pragma unroll
            for (int i = 0; i < 16; ++i) {
                int s = t + 256 * i;
                int r = s >> 4, kl = s & 15;
                gout[k0 + kl + (r << 16)] = tile[kl * 256 + (r ^ kl)];
            }
        }
    }
}

extern "C" void kernel_launch(void* const* d_in, const int* in_sizes, int n_in,
                              void* d_out, int out_size, void* d_ws, size_t ws_size,
                              hipStream_t stream) {
    const float* a = (const float*)d_in[0];
    const float* x = (const float*)d_in[1];
    float2* out2 = (float2*)d_out;

    float2* buf0 = (float2*)d_ws;       // 128 MB
    float2* buf1 = buf0 + N2;           // 128 MB

    dim3 b(256);
    // forward FFT of z = a + i*x, length 2^24 (3 passes)
    fft_pass<0><<<4096, b, 0, stream>>>(a, x, nullptr, buf0, nullptr);
    fft_pass<1><<<4096, b, 0, stream>>>(nullptr, nullptr, buf0, buf1, nullptr);
    fft_pass<2><<<4096, b, 0, stream>>>(nullptr, nullptr, buf1, buf0, nullptr);
    // inverse via half-length forward FFT of P (length 2^23, 3 passes)
    fft_pass<3><<<2048, b, 0, stream>>>(nullptr, nullptr, buf0, buf1, nullptr);
    fft_pass<4><<<2048, b, 0, stream>>>(nullptr, nullptr, buf1, buf0, nullptr);
    fft_pass<5><<<2048, b, 0, stream>>>(nullptr, nullptr, buf0, nullptr, out2);
}

// Round 4
// 326.856 us; speedup vs baseline: 1.3183x; 1.3183x over previous
//
#include <hip/hip_runtime.h>

#define N_SIG (1 << 23)   // 8388608
#define N2    (1 << 24)   // padded FFT length = 256^3
#define MH    (1 << 23)   // half length M = 2^23 = 256*256*128

// ---------------------------------------------------------------------------
// complex helpers
// ---------------------------------------------------------------------------
__device__ __forceinline__ float2 cadd(float2 a, float2 b) { return make_float2(a.x + b.x, a.y + b.y); }
__device__ __forceinline__ float2 csub(float2 a, float2 b) { return make_float2(a.x - b.x, a.y - b.y); }
__device__ __forceinline__ float2 cmul(float2 a, float2 b) {
    return make_float2(fmaf(a.x, b.x, -(a.y * b.y)), fmaf(a.x, b.y, a.y * b.x));
}
__device__ __forceinline__ float2 mulnegi(float2 a) { return make_float2(a.y, -a.x); }  // -i*a

// exp(-2*pi*i*f), f in revolutions
__device__ __forceinline__ float2 twid(float f) {
    float s, c;
#if __has_builtin(__builtin_amdgcn_sinf) && __has_builtin(__builtin_amdgcn_cosf)
    s = __builtin_amdgcn_sinf(f);
    c = __builtin_amdgcn_cosf(f);
#else
    __sincosf(6.28318530717958647693f * f, &s, &c);
#endif
    return make_float2(c, -s);
}

// radix-4 DIF butterfly = natural-order 4-point DFT (negative exponent)
__device__ __forceinline__ void bfly4(float2 c0, float2 c1, float2 c2, float2 c3,
                                      float2& e0, float2& e1, float2& e2, float2& e3) {
    float2 d0 = cadd(c0, c2), d1 = csub(c0, c2);
    float2 d2 = cadd(c1, c3), d3 = mulnegi(csub(c1, c3));
    e0 = cadd(d0, d2); e1 = cadd(d1, d3); e2 = csub(d0, d2); e3 = csub(d1, d3);
}

// 16-point DFT, natural order in/out
__device__ __forceinline__ void fft16(float2 v[16]) {
    const float C1 = 0.92387953251128675613f;
    const float S1 = 0.38268343236508977173f;
    const float RH = 0.70710678118654752440f;
    const float2 W1 = make_float2( C1, -S1);
    const float2 W2 = make_float2( RH, -RH);
    const float2 W3 = make_float2( S1, -C1);
    const float2 W6 = make_float2(-RH, -RH);
    const float2 W9 = make_float2(-C1,  S1);
    float2 t[16];
    { float2 e0,e1,e2,e3; bfly4(v[0],v[4],v[8],v[12], e0,e1,e2,e3);
      t[0]=e0; t[1]=e1; t[2]=e2; t[3]=e3; }
    { float2 e0,e1,e2,e3; bfly4(v[1],v[5],v[9],v[13], e0,e1,e2,e3);
      t[4]=e0; t[5]=cmul(e1,W1); t[6]=cmul(e2,W2); t[7]=cmul(e3,W3); }
    { float2 e0,e1,e2,e3; bfly4(v[2],v[6],v[10],v[14], e0,e1,e2,e3);
      t[8]=e0; t[9]=cmul(e1,W2); t[10]=mulnegi(e2); t[11]=cmul(e3,W6); }
    { float2 e0,e1,e2,e3; bfly4(v[3],v[7],v[11],v[15], e0,e1,e2,e3);
      t[12]=e0; t[13]=cmul(e1,W3); t[14]=cmul(e2,W6); t[15]=cmul(e3,W9); }
    { float2 e0,e1,e2,e3; bfly4(t[0],t[4],t[8],t[12], e0,e1,e2,e3);
      v[0]=e0; v[4]=e1; v[8]=e2; v[12]=e3; }
    { float2 e0,e1,e2,e3; bfly4(t[1],t[5],t[9],t[13], e0,e1,e2,e3);
      v[1]=e0; v[5]=e1; v[9]=e2; v[13]=e3; }
    { float2 e0,e1,e2,e3; bfly4(t[2],t[6],t[10],t[14], e0,e1,e2,e3);
      v[2]=e0; v[6]=e1; v[10]=e2; v[14]=e3; }
    { float2 e0,e1,e2,e3; bfly4(t[3],t[7],t[11],t[15], e0,e1,e2,e3);
      v[3]=e0; v[7]=e1; v[11]=e2; v[15]=e3; }
}

// 8-point DFT, natural order in/out
__device__ __forceinline__ void fft8(float2 v[8]) {
    const float RH = 0.70710678118654752440f;
    float2 e0,e1,e2,e3, o0,o1,o2,o3;
    bfly4(v[0],v[2],v[4],v[6], e0,e1,e2,e3);
    bfly4(v[1],v[3],v[5],v[7], o0,o1,o2,o3);
    o1 = cmul(o1, make_float2( RH,-RH));
    o2 = mulnegi(o2);
    o3 = cmul(o3, make_float2(-RH,-RH));
    v[0]=cadd(e0,o0); v[4]=csub(e0,o0);
    v[1]=cadd(e1,o1); v[5]=csub(e1,o1);
    v[2]=cadd(e2,o2); v[6]=csub(e2,o2);
    v[3]=cadd(e3,o3); v[7]=csub(e3,o3);
}

// W[k] = FA[k]*FX[k] = -(i/4)*(zk^2 - conj(zr)^2), zk=Z[k], zr=Z[N2-k]
__device__ __forceinline__ float2 Wfun(float2 zk, float2 zr) {
    float ax = zk.x*zk.x - zk.y*zk.y, ay = 2.f*zk.x*zk.y;
    float bx = zr.x*zr.x - zr.y*zr.y, by = -2.f*zr.x*zr.y;
    float dx = ax - bx, dy = ay - by;
    return make_float2(0.25f*dy, -0.25f*dx);
}

// ---------------------------------------------------------------------------
// MODE 0: fwd stage A  (N2, radix-256, l=65536), pack fused
// MODE 1: fwd stage B  (N2, radix-256, l=256)
// MODE 2: fwd stage C  (N2, radix-256, l=1)
// MODE 3: inv stage A  (M,  radix-256, l=32768), Hermitian-pack fused
// MODE 4: inv stage B  (M,  radix-256, l=128)
// MODE 5: inv stage C  (M,  radix-128, l=1), interleaved real output
// Geometry (proven in round 2): 512 threads, 32 rows x 256 (or 64 rows x 128),
// 64 KiB LDS, launch_bounds(512,4) -> VGPR<=128, no spill.
// ---------------------------------------------------------------------------
template<int MODE>
__global__ __launch_bounds__(512, 4)
void fft_pass(const float* __restrict__ ga, const float* __restrict__ gx,
              const float2* __restrict__ gin, float2* __restrict__ gout) {
    __shared__ float2 tile[8192];   // 64 KB
    const int t   = threadIdx.x;
    const int blk = blockIdx.x;

    if constexpr (MODE == 5) {
        // ---- radix-128 final pass: 64 rows x 128 pts, slot in [0,8) ----
        const int row  = t & 63;
        const int slot = t >> 6;
        const int mask = row & 15;
        const int bi   = blk * 64 + row;

        // q = u1 + 16*u2; this thread owns u1 in {slot, slot+8}
        float2 va[8], vb[8];
        #pragma unroll
        for (int u2 = 0; u2 < 8; ++u2)
            va[u2] = gin[bi + ((slot + 16 * u2) << 16)];
        #pragma unroll
        for (int u2 = 0; u2 < 8; ++u2)
            vb[u2] = gin[bi + ((slot + 8 + 16 * u2) << 16)];
        fft8(va); fft8(vb);
        #pragma unroll
        for (int r2 = 1; r2 < 8; ++r2)
            va[r2] = cmul(va[r2], twid((float)(slot * r2) * (1.0f / 128.0f)));
        #pragma unroll
        for (int r2 = 1; r2 < 8; ++r2)
            vb[r2] = cmul(vb[r2], twid((float)((slot + 8) * r2) * (1.0f / 128.0f)));
        #pragma unroll
        for (int r2 = 0; r2 < 8; ++r2)
            tile[row * 128 + ((slot + 16 * r2) ^ mask)] = va[r2];
        #pragma unroll
        for (int r2 = 0; r2 < 8; ++r2)
            tile[row * 128 + ((slot + 8 + 16 * r2) ^ mask)] = vb[r2];
        __syncthreads();

        // layer 2: FFT16 over u1 for fixed r2 = slot
        float2 w[16];
        #pragma unroll
        for (int q1 = 0; q1 < 16; ++q1)
            w[q1] = tile[row * 128 + ((q1 + 16 * slot) ^ mask)];
        __syncthreads();
        fft16(w);   // w[r1] -> output r = slot + 8*r1

        // keep r < 64 (m = k + 65536 r < 2^22), y[2m]=Re/M, y[2m+1]=-Im/M
        const float sc = 1.0f / 8388608.0f;
        #pragma unroll
        for (int r1 = 0; r1 < 8; ++r1) {
            int r = slot + 8 * r1;
            tile[row * 64 + (r ^ mask)] = make_float2(w[r1].x * sc, -w[r1].y * sc);
        }
        __syncthreads();
        const int k0 = blk * 64;
        #pragma unroll
        for (int i = 0; i < 8; ++i) {
            int s = t + 512 * i;               // 64*64 = 4096 float2
            int r = s >> 6, kl = s & 63;
            gout[k0 + kl + (r << 16)] = tile[kl * 64 + (r ^ (kl & 15))];
        }
        return;
    } else {
        // ---- radix-256 pass: 32 rows x 256 pts, slot in [0,16) ----
        const int row  = t & 31;
        const int slot = t >> 5;
        const int mask = row & 15;
        float2 v[16];
        int jt = 0;

        if constexpr (MODE == 0) {          // fwd A, pack fused (q>=128 zero)
            int j = blk * 32 + row;
            jt = j;
            #pragma unroll
            for (int u2 = 0; u2 < 16; ++u2) {
                if (u2 < 8) {
                    int g = j + ((slot + 16 * u2) << 16);   // < N_SIG
                    v[u2] = make_float2(ga[g], gx[g]);
                } else {
                    v[u2] = make_float2(0.f, 0.f);
                }
            }
        } else if constexpr (MODE == 3) {   // inv A, Hermitian pack fused
            int j = blk * 32 + row;
            jt = j;
            #pragma unroll
            for (int u2 = 0; u2 < 16; ++u2) {
                int tp = j + ((slot + 16 * u2) << 15);      // [0, M)
                float2 z1 = gin[tp];                        // Z[t]
                float2 z2 = gin[tp + MH];                   // Z[t+M]
                float2 z3 = gin[(N2 - tp) & (N2 - 1)];      // Z[N2-t]
                float2 z4 = gin[MH - tp];                   // Z[M-t]
                float2 w1 = Wfun(z1, z3);                   // W[t]
                float2 w2 = Wfun(z2, z4);                   // W[t+M]
                float2 S = make_float2(0.5f * (w1.x + w2.x), 0.5f * (w1.y + w2.y));
                float2 D = make_float2(0.5f * (w1.x - w2.x), 0.5f * (w1.y - w2.y));
                float2 tw = twid((float)tp * (1.0f / 16777216.0f));
                float c = tw.x, s = -tw.y;                  // e^{+2pi i t/N2}
                float2 T = make_float2(c * D.x - s * D.y, c * D.y + s * D.x);
                // U = S + i*T ; P = conj(U)
                v[u2] = make_float2(S.x - T.y, -(S.y + T.x));
            }
        } else if constexpr (MODE == 1) {   // fwd B
            int jB = blk >> 3, k0 = (blk & 7) * 32;
            int bi = k0 + row + (jB << 8);
            jt = jB;
            #pragma unroll
            for (int u2 = 0; u2 < 16; ++u2)
                v[u2] = gin[bi + ((slot + 16 * u2) << 16)];
        } else if constexpr (MODE == 4) {   // inv B (half length, stride 2^15)
            int jB = blk >> 3, k0 = (blk & 7) * 32;
            int bi = k0 + row + (jB << 8);
            jt = jB;
            #pragma unroll
            for (int u2 = 0; u2 < 16; ++u2)
                v[u2] = gin[bi + ((slot + 16 * u2) << 15)];
        } else {                            // MODE 2: fwd C
            int bi = blk * 32 + row;
            #pragma unroll
            for (int u2 = 0; u2 < 16; ++u2)
                v[u2] = gin[bi + ((slot + 16 * u2) << 16)];
        }

        // layer 1: FFT16 over u2, inter-layer twiddle W256^{slot*r}
        fft16(v);
        #pragma unroll
        for (int r = 1; r < 16; ++r)
            v[r] = cmul(v[r], twid((float)(slot * r) * (1.0f / 256.0f)));
        #pragma unroll
        for (int r = 0; r < 16; ++r)
            tile[row * 256 + ((slot + 16 * r) ^ mask)] = v[r];
        __syncthreads();

        // layer 2: FFT16 over u1
        float2 w[16];
        #pragma unroll
        for (int u1 = 0; u1 < 16; ++u1)
            w[u1] = tile[row * 256 + ((u1 + (slot << 4)) ^ mask)];
        __syncthreads();
        fft16(w);

        // outer twiddle W_{R*l}^{jt*r}, r = slot + 16*v2
        if constexpr (MODE == 0) {
            #pragma unroll
            for (int v2 = 0; v2 < 16; ++v2) {
                int r = slot + 16 * v2;
                w[v2] = cmul(w[v2], twid((float)(jt * r) * (1.0f / 16777216.0f)));
            }
        } else if constexpr (MODE == 3) {
            #pragma unroll
            for (int v2 = 0; v2 < 16; ++v2) {
                int r = slot + 16 * v2;
                w[v2] = cmul(w[v2], twid((float)(jt * r) * (1.0f / 8388608.0f)));
            }
        } else if constexpr (MODE == 1) {
            #pragma unroll
            for (int v2 = 0; v2 < 16; ++v2) {
                int r = slot + 16 * v2;
                w[v2] = cmul(w[v2], twid((float)(jt * r) * (1.0f / 65536.0f)));
            }
        } else if constexpr (MODE == 4) {
            #pragma unroll
            for (int v2 = 0; v2 < 16; ++v2) {
                int r = slot + 16 * v2;
                w[v2] = cmul(w[v2], twid((float)(jt * r) * (1.0f / 32768.0f)));
            }
        }

        // stage to LDS, cooperative coalesced store
        #pragma unroll
        for (int v2 = 0; v2 < 16; ++v2)
            tile[row * 256 + ((slot + (v2 << 4)) ^ mask)] = w[v2];
        __syncthreads();

        if constexpr (MODE == 0 || MODE == 3) {       // out[256 j + r]: linear
            int base = blk << 13;
            #pragma unroll
            for (int i = 0; i < 16; ++i) {
                int s = t + 512 * i;
                int rr = s >> 8, c = s & 255;
                gout[base + s] = tile[rr * 256 + (c ^ (rr & 15))];
            }
        } else if constexpr (MODE == 1 || MODE == 4) {// out[k + 65536 j + 256 r]
            int jB = blk >> 3, k0 = (blk & 7) * 32;
            int base = k0 + (jB << 16);
            #pragma unroll
            for (int i = 0; i < 16; ++i) {
                int s = t + 512 * i;
                int r = s >> 5, kl = s & 31;
                gout[base + kl + (r << 8)] = tile[kl * 256 + (r ^ (kl & 15))];
            }
        } else {                                      // MODE 2: out[k + 65536 r]
            int k0 = blk * 32;
            #pragma unroll
            for (int i = 0; i < 16; ++i) {
                int s = t + 512 * i;
                int r = s >> 5, kl = s & 31;
                gout[k0 + kl + (r << 16)] = tile[kl * 256 + (r ^ (kl & 15))];
            }
        }
    }
}

extern "C" void kernel_launch(void* const* d_in, const int* in_sizes, int n_in,
                              void* d_out, int out_size, void* d_ws, size_t ws_size,
                              hipStream_t stream) {
    const float* a = (const float*)d_in[0];
    const float* x = (const float*)d_in[1];
    float2* out2 = (float2*)d_out;

    float2* buf0 = (float2*)d_ws;       // 128 MB
    float2* buf1 = buf0 + N2;           // 128 MB

    dim3 b(512);
    // forward FFT of z = a + i*x, length 2^24 (3 passes, 32-row tiles)
    fft_pass<0><<<2048, b, 0, stream>>>(a, x, nullptr, buf0);
    fft_pass<1><<<2048, b, 0, stream>>>(nullptr, nullptr, buf0, buf1);
    fft_pass<2><<<2048, b, 0, stream>>>(nullptr, nullptr, buf1, buf0);
    // inverse via half-length forward FFT of P (length 2^23, 3 passes)
    fft_pass<3><<<1024, b, 0, stream>>>(nullptr, nullptr, buf0, buf1);
    fft_pass<4><<<1024, b, 0, stream>>>(nullptr, nullptr, buf1, buf0);
    fft_pass<5><<<1024, b, 0, stream>>>(nullptr, nullptr, buf0, out2);
}

// Round 5
// 235.517 us; speedup vs baseline: 1.8296x; 1.3878x over previous
//
#include <hip/hip_runtime.h>

#define N_SIG (1 << 23)   // 8388608
#define N2    (1 << 24)   // padded FFT length = 256^3
#define MH    (1 << 23)   // half length M = 2^23 = 256*256*128

// ---------------------------------------------------------------------------
// complex helpers
// ---------------------------------------------------------------------------
__device__ __forceinline__ float2 cadd(float2 a, float2 b) { return make_float2(a.x + b.x, a.y + b.y); }
__device__ __forceinline__ float2 csub(float2 a, float2 b) { return make_float2(a.x - b.x, a.y - b.y); }
__device__ __forceinline__ float2 cmul(float2 a, float2 b) {
    return make_float2(fmaf(a.x, b.x, -(a.y * b.y)), fmaf(a.x, b.y, a.y * b.x));
}
__device__ __forceinline__ float2 mulnegi(float2 a) { return make_float2(a.y, -a.x); }  // -i*a

// exp(-2*pi*i*f), f in revolutions
__device__ __forceinline__ float2 twid(float f) {
    float s, c;
#if __has_builtin(__builtin_amdgcn_sinf) && __has_builtin(__builtin_amdgcn_cosf)
    s = __builtin_amdgcn_sinf(f);
    c = __builtin_amdgcn_cosf(f);
#else
    __sincosf(6.28318530717958647693f * f, &s, &c);
#endif
    return make_float2(c, -s);
}

// radix-4 DIF butterfly = natural-order 4-point DFT (negative exponent)
__device__ __forceinline__ void bfly4(float2 c0, float2 c1, float2 c2, float2 c3,
                                      float2& e0, float2& e1, float2& e2, float2& e3) {
    float2 d0 = cadd(c0, c2), d1 = csub(c0, c2);
    float2 d2 = cadd(c1, c3), d3 = mulnegi(csub(c1, c3));
    e0 = cadd(d0, d2); e1 = cadd(d1, d3); e2 = csub(d0, d2); e3 = csub(d1, d3);
}

// 16-point DFT, natural order in/out
__device__ __forceinline__ void fft16(float2 v[16]) {
    const float C1 = 0.92387953251128675613f;
    const float S1 = 0.38268343236508977173f;
    const float RH = 0.70710678118654752440f;
    const float2 W1 = make_float2( C1, -S1);
    const float2 W2 = make_float2( RH, -RH);
    const float2 W3 = make_float2( S1, -C1);
    const float2 W6 = make_float2(-RH, -RH);
    const float2 W9 = make_float2(-C1,  S1);
    float2 t[16];
    { float2 e0,e1,e2,e3; bfly4(v[0],v[4],v[8],v[12], e0,e1,e2,e3);
      t[0]=e0; t[1]=e1; t[2]=e2; t[3]=e3; }
    { float2 e0,e1,e2,e3; bfly4(v[1],v[5],v[9],v[13], e0,e1,e2,e3);
      t[4]=e0; t[5]=cmul(e1,W1); t[6]=cmul(e2,W2); t[7]=cmul(e3,W3); }
    { float2 e0,e1,e2,e3; bfly4(v[2],v[6],v[10],v[14], e0,e1,e2,e3);
      t[8]=e0; t[9]=cmul(e1,W2); t[10]=mulnegi(e2); t[11]=cmul(e3,W6); }
    { float2 e0,e1,e2,e3; bfly4(v[3],v[7],v[11],v[15], e0,e1,e2,e3);
      t[12]=e0; t[13]=cmul(e1,W3); t[14]=cmul(e2,W6); t[15]=cmul(e3,W9); }
    { float2 e0,e1,e2,e3; bfly4(t[0],t[4],t[8],t[12], e0,e1,e2,e3);
      v[0]=e0; v[4]=e1; v[8]=e2; v[12]=e3; }
    { float2 e0,e1,e2,e3; bfly4(t[1],t[5],t[9],t[13], e0,e1,e2,e3);
      v[1]=e0; v[5]=e1; v[9]=e2; v[13]=e3; }
    { float2 e0,e1,e2,e3; bfly4(t[2],t[6],t[10],t[14], e0,e1,e2,e3);
      v[2]=e0; v[6]=e1; v[10]=e2; v[14]=e3; }
    { float2 e0,e1,e2,e3; bfly4(t[3],t[7],t[11],t[15], e0,e1,e2,e3);
      v[3]=e0; v[7]=e1; v[11]=e2; v[15]=e3; }
}

// 8-point DFT, natural order in/out
__device__ __forceinline__ void fft8(float2 v[8]) {
    const float RH = 0.70710678118654752440f;
    float2 e0,e1,e2,e3, o0,o1,o2,o3;
    bfly4(v[0],v[2],v[4],v[6], e0,e1,e2,e3);
    bfly4(v[1],v[3],v[5],v[7], o0,o1,o2,o3);
    o1 = cmul(o1, make_float2( RH,-RH));
    o2 = mulnegi(o2);
    o3 = cmul(o3, make_float2(-RH,-RH));
    v[0]=cadd(e0,o0); v[4]=csub(e0,o0);
    v[1]=cadd(e1,o1); v[5]=csub(e1,o1);
    v[2]=cadd(e2,o2); v[6]=csub(e2,o2);
    v[3]=cadd(e3,o3); v[7]=csub(e3,o3);
}

// W[k] = FA[k]*FX[k] = -(i/4)*(zk^2 - conj(zr)^2), zk=Z[k], zr=Z[N2-k]
__device__ __forceinline__ float2 Wfun(float2 zk, float2 zr) {
    float ax = zk.x*zk.x - zk.y*zk.y, ay = 2.f*zk.x*zk.y;
    float bx = zr.x*zr.x - zr.y*zr.y, by = -2.f*zr.x*zr.y;
    float dx = ax - bx, dy = ay - by;
    return make_float2(0.25f*dy, -0.25f*dx);
}

// ---------------------------------------------------------------------------
// Paired Hermitian pointwise: thread t in [0, M/2] computes P[t] and P[M-t]
// from the shared 4-tuple {Z[t], Z[t+M], Z[N2-t], Z[M-t]} -> each Z line is
// fetched exactly once across the grid. Low-VGPR streaming kernel (no spill).
//   S = (W[t]+W[t+M])/2, D = (W[t]-W[t+M])/2, T = e^{+2pi i t/N2} * D
//   P[t] = conj(S + iT)
// ---------------------------------------------------------------------------
__global__ __launch_bounds__(512)
void pw_kernel(const float2* __restrict__ Z, float2* __restrict__ P) {
    int t = blockIdx.x * blockDim.x + threadIdx.x;
    if (t > (MH / 2)) return;
    float2 z1 = Z[t];                    // Z[t]
    float2 z2 = Z[t + MH];               // Z[t+M]
    float2 z3 = Z[(N2 - t) & (N2 - 1)];  // Z[N2-t]
    float2 z4 = Z[MH - t];               // Z[M-t]

    float2 Wt  = Wfun(z1, z3);           // W[t]
    float2 WtM = Wfun(z2, z4);           // W[t+M]   (Z[N2-(t+M)] = Z[M-t])

    float2 e = twid((float)t * (1.0f / 16777216.0f));  // (cos th, -sin th)
    float c = e.x, s = -e.y;             // th = +2pi t / N2

    {   // P[t]
        float Sx = 0.5f*(Wt.x + WtM.x), Sy = 0.5f*(Wt.y + WtM.y);
        float Dx = 0.5f*(Wt.x - WtM.x), Dy = 0.5f*(Wt.y - WtM.y);
        float Tx = c*Dx - s*Dy, Ty = c*Dy + s*Dx;
        P[t] = make_float2(Sx - Ty, -(Sy + Tx));
    }
    if (t >= 1) {   // P[M-t]  (t=M/2 rewrites the same value: idempotent)
        float2 Wt2  = Wfun(z4, z2);      // W[M-t]  (Z[N2-(M-t)] = Z[M+t])
        float2 Wt2M = Wfun(z3, z1);      // W[N2-t] (Z[N2-(N2-t)] = Z[t])
        float Sx = 0.5f*(Wt2.x + Wt2M.x), Sy = 0.5f*(Wt2.y + Wt2M.y);
        float Dx = 0.5f*(Wt2.x - Wt2M.x), Dy = 0.5f*(Wt2.y - Wt2M.y);
        // e^{+2pi i (M-t)/N2} = (-c, s)
        float Tx = -c*Dx - s*Dy, Ty = -c*Dy + s*Dx;
        P[MH - t] = make_float2(Sx - Ty, -(Sy + Tx));
    }
}

// ---------------------------------------------------------------------------
// MODE 0: fwd stage A  (N2, radix-256, l=65536), pack fused
// MODE 1: fwd stage B  (N2, radix-256, l=256)
// MODE 2: fwd stage C  (N2, radix-256, l=1)
// MODE 3: inv stage A  (M,  radix-256, l=32768), plain linear read of P
// MODE 4: inv stage B  (M,  radix-256, l=128)
// MODE 5: inv stage C  (M,  radix-128, l=1), interleaved real output
// Geometry: 512 threads, 32 rows x 256 (or 64 rows x 128), 64 KiB LDS.
// ---------------------------------------------------------------------------
template<int MODE>
__global__ __launch_bounds__(512, 4)
void fft_pass(const float* __restrict__ ga, const float* __restrict__ gx,
              const float2* __restrict__ gin, float2* __restrict__ gout) {
    __shared__ float2 tile[8192];   // 64 KB
    const int t   = threadIdx.x;
    const int blk = blockIdx.x;

    if constexpr (MODE == 5) {
        // ---- radix-128 final pass: 64 rows x 128 pts, slot in [0,8) ----
        const int row  = t & 63;
        const int slot = t >> 6;
        const int mask = row & 15;
        const int bi   = blk * 64 + row;

        float2 va[8], vb[8];
        #pragma unroll
        for (int u2 = 0; u2 < 8; ++u2)
            va[u2] = gin[bi + ((slot + 16 * u2) << 16)];
        #pragma unroll
        for (int u2 = 0; u2 < 8; ++u2)
            vb[u2] = gin[bi + ((slot + 8 + 16 * u2) << 16)];
        fft8(va); fft8(vb);
        #pragma unroll
        for (int r2 = 1; r2 < 8; ++r2)
            va[r2] = cmul(va[r2], twid((float)(slot * r2) * (1.0f / 128.0f)));
        #pragma unroll
        for (int r2 = 1; r2 < 8; ++r2)
            vb[r2] = cmul(vb[r2], twid((float)((slot + 8) * r2) * (1.0f / 128.0f)));
        #pragma unroll
        for (int r2 = 0; r2 < 8; ++r2)
            tile[row * 128 + ((slot + 16 * r2) ^ mask)] = va[r2];
        #pragma unroll
        for (int r2 = 0; r2 < 8; ++r2)
            tile[row * 128 + ((slot + 8 + 16 * r2) ^ mask)] = vb[r2];
        __syncthreads();

        float2 w[16];
        #pragma unroll
        for (int q1 = 0; q1 < 16; ++q1)
            w[q1] = tile[row * 128 + ((q1 + 16 * slot) ^ mask)];
        __syncthreads();
        fft16(w);   // w[r1] -> output r = slot + 8*r1

        // keep r < 64 (m = k + 65536 r < 2^22), y[2m]=Re/M, y[2m+1]=-Im/M
        const float sc = 1.0f / 8388608.0f;
        #pragma unroll
        for (int r1 = 0; r1 < 8; ++r1) {
            int r = slot + 8 * r1;
            tile[row * 64 + (r ^ mask)] = make_float2(w[r1].x * sc, -w[r1].y * sc);
        }
        __syncthreads();
        const int k0 = blk * 64;
        #pragma unroll
        for (int i = 0; i < 8; ++i) {
            int s = t + 512 * i;               // 64*64 = 4096 float2
            int r = s >> 6, kl = s & 63;
            gout[k0 + kl + (r << 16)] = tile[kl * 64 + (r ^ (kl & 15))];
        }
        return;
    } else {
        // ---- radix-256 pass: 32 rows x 256 pts, slot in [0,16) ----
        const int row  = t & 31;
        const int slot = t >> 5;
        const int mask = row & 15;
        float2 v[16];
        int jt = 0;

        if constexpr (MODE == 0) {          // fwd A, pack fused (q>=128 zero)
            int j = blk * 32 + row;
            jt = j;
            #pragma unroll
            for (int u2 = 0; u2 < 16; ++u2) {
                if (u2 < 8) {
                    int g = j + ((slot + 16 * u2) << 16);   // < N_SIG
                    v[u2] = make_float2(ga[g], gx[g]);
                } else {
                    v[u2] = make_float2(0.f, 0.f);
                }
            }
        } else if constexpr (MODE == 3) {   // inv A: plain linear read of P
            int j = blk * 32 + row;          // j in [0, 2^15)
            jt = j;
            #pragma unroll
            for (int u2 = 0; u2 < 16; ++u2)
                v[u2] = gin[j + ((slot + 16 * u2) << 15)];
        } else if constexpr (MODE == 1) {   // fwd B
            int jB = blk >> 3, k0 = (blk & 7) * 32;
            int bi = k0 + row + (jB << 8);
            jt = jB;
            #pragma unroll
            for (int u2 = 0; u2 < 16; ++u2)
                v[u2] = gin[bi + ((slot + 16 * u2) << 16)];
        } else if constexpr (MODE == 4) {   // inv B (half length, stride 2^15)
            int jB = blk >> 3, k0 = (blk & 7) * 32;
            int bi = k0 + row + (jB << 8);
            jt = jB;
            #pragma unroll
            for (int u2 = 0; u2 < 16; ++u2)
                v[u2] = gin[bi + ((slot + 16 * u2) << 15)];
        } else {                            // MODE 2: fwd C
            int bi = blk * 32 + row;
            #pragma unroll
            for (int u2 = 0; u2 < 16; ++u2)
                v[u2] = gin[bi + ((slot + 16 * u2) << 16)];
        }

        // layer 1: FFT16 over u2, inter-layer twiddle W256^{slot*r}
        fft16(v);
        #pragma unroll
        for (int r = 1; r < 16; ++r)
            v[r] = cmul(v[r], twid((float)(slot * r) * (1.0f / 256.0f)));
        #pragma unroll
        for (int r = 0; r < 16; ++r)
            tile[row * 256 + ((slot + 16 * r) ^ mask)] = v[r];
        __syncthreads();

        // layer 2: FFT16 over u1
        float2 w[16];
        #pragma unroll
        for (int u1 = 0; u1 < 16; ++u1)
            w[u1] = tile[row * 256 + ((u1 + (slot << 4)) ^ mask)];
        __syncthreads();
        fft16(w);

        // outer twiddle W_{R*l}^{jt*r}, r = slot + 16*v2
        if constexpr (MODE == 0) {
            #pragma unroll
            for (int v2 = 0; v2 < 16; ++v2) {
                int r = slot + 16 * v2;
                w[v2] = cmul(w[v2], twid((float)(jt * r) * (1.0f / 16777216.0f)));
            }
        } else if constexpr (MODE == 3) {
            #pragma unroll
            for (int v2 = 0; v2 < 16; ++v2) {
                int r = slot + 16 * v2;
                w[v2] = cmul(w[v2], twid((float)(jt * r) * (1.0f / 8388608.0f)));
            }
        } else if constexpr (MODE == 1) {
            #pragma unroll
            for (int v2 = 0; v2 < 16; ++v2) {
                int r = slot + 16 * v2;
                w[v2] = cmul(w[v2], twid((float)(jt * r) * (1.0f / 65536.0f)));
            }
        } else if constexpr (MODE == 4) {
            #pragma unroll
            for (int v2 = 0; v2 < 16; ++v2) {
                int r = slot + 16 * v2;
                w[v2] = cmul(w[v2], twid((float)(jt * r) * (1.0f / 32768.0f)));
            }
        }

        // stage to LDS, cooperative coalesced store
        #pragma unroll
        for (int v2 = 0; v2 < 16; ++v2)
            tile[row * 256 + ((slot + (v2 << 4)) ^ mask)] = w[v2];
        __syncthreads();

        if constexpr (MODE == 0 || MODE == 3) {       // out[256 j + r]: linear
            int base = blk << 13;
            #pragma unroll
            for (int i = 0; i < 16; ++i) {
                int s = t + 512 * i;
                int rr = s >> 8, c = s & 255;
                gout[base + s] = tile[rr * 256 + (c ^ (rr & 15))];
            }
        } else if constexpr (MODE == 1 || MODE == 4) {// out[k + 65536 j + 256 r]
            int jB = blk >> 3, k0 = (blk & 7) * 32;
            int base = k0 + (jB << 16);
            #pragma unroll
            for (int i = 0; i < 16; ++i) {
                int s = t + 512 * i;
                int r = s >> 5, kl = s & 31;
                gout[base + kl + (r << 8)] = tile[kl * 256 + (r ^ (kl & 15))];
            }
        } else {                                      // MODE 2: out[k + 65536 r]
            int k0 = blk * 32;
            #pragma unroll
            for (int i = 0; i < 16; ++i) {
                int s = t + 512 * i;
                int r = s >> 5, kl = s & 31;
                gout[k0 + kl + (r << 16)] = tile[kl * 256 + (r ^ (kl & 15))];
            }
        }
    }
}

extern "C" void kernel_launch(void* const* d_in, const int* in_sizes, int n_in,
                              void* d_out, int out_size, void* d_ws, size_t ws_size,
                              hipStream_t stream) {
    const float* a = (const float*)d_in[0];
    const float* x = (const float*)d_in[1];
    float2* out2 = (float2*)d_out;

    float2* buf0 = (float2*)d_ws;       // 128 MB
    float2* buf1 = buf0 + N2;           // 128 MB

    dim3 b(512);
    // forward FFT of z = a + i*x, length 2^24 (3 passes)
    fft_pass<0><<<2048, b, 0, stream>>>(a, x, nullptr, buf0);
    fft_pass<1><<<2048, b, 0, stream>>>(nullptr, nullptr, buf0, buf1);
    fft_pass<2><<<2048, b, 0, stream>>>(nullptr, nullptr, buf1, buf0);
    // paired Hermitian pointwise: Z (buf0) -> P (buf1), each Z line read once
    pw_kernel<<<8193, b, 0, stream>>>(buf0, buf1);
    // inverse via half-length forward FFT of P (length 2^23, 3 passes)
    fft_pass<3><<<1024, b, 0, stream>>>(nullptr, nullptr, buf1, buf0);
    fft_pass<4><<<1024, b, 0, stream>>>(nullptr, nullptr, buf0, buf1);
    fft_pass<5><<<1024, b, 0, stream>>>(nullptr, nullptr, buf1, out2);
}